// Round 1
// baseline (862.972 us; speedup 1.0000x reference)
//
#include <hip/hip_runtime.h>
#include <stdint.h>

#define N_TOK 32768
#define DIN   2048
#define DOUT  2048
#define LAD   8
#define RRK   16
#define KCAT  2176   /* DIN + LAD*RRK */
#define SCALE 2.0f

typedef __attribute__((ext_vector_type(8))) short bf16x8;
typedef __attribute__((ext_vector_type(4))) float f32x4;

__device__ __forceinline__ unsigned short f2bf(float f) {
    union { float f; unsigned u; } c; c.f = f;
    return (unsigned short)((c.u + 0x7FFFu + ((c.u >> 16) & 1u)) >> 16);
}

__device__ __forceinline__ uint4 pack8(float4 a, float4 b) {
    union { unsigned short s[8]; uint4 v; } u;
    u.s[0] = f2bf(a.x); u.s[1] = f2bf(a.y); u.s[2] = f2bf(a.z); u.s[3] = f2bf(a.w);
    u.s[4] = f2bf(b.x); u.s[5] = f2bf(b.y); u.s[6] = f2bf(b.z); u.s[7] = f2bf(b.w);
    return u.v;
}

__device__ __forceinline__ void async16(const void* g, void* l) {
    __builtin_amdgcn_global_load_lds(
        (const __attribute__((address_space(1))) void*)g,
        (__attribute__((address_space(3))) void*)l, 16, 0, 0);
}

// ---------------------------------------------------------------------------
// P0: build Wcat = [bf16(W) | B_all gathered as [o][l*16+r]]  (DOUT x KCAT)
//     and Acat = bf16(A_all) viewed flat as [128][DIN]
// ---------------------------------------------------------------------------
__global__ __launch_bounds__(256) void prep_w(const float* __restrict__ W,
                                              const float* __restrict__ A_all,
                                              const float* __restrict__ B_all,
                                              unsigned short* __restrict__ wcat,
                                              unsigned short* __restrict__ acat) {
    const int NW = DOUT * DIN / 8;       // 524288 threads: W base convert
    const int NB = DOUT * LAD;           // 16384 threads: B_all tail gather
    const int NA = LAD * RRK * DIN / 8;  // 32768 threads: Acat convert
    int tid = blockIdx.x * 256 + threadIdx.x;
    if (tid < NW) {
        int e = tid * 8;
        int o = e / DIN, k = e % DIN;
        float4 f0 = *(const float4*)(W + e);
        float4 f1 = *(const float4*)(W + e + 4);
        *(uint4*)(wcat + (size_t)o * KCAT + k) = pack8(f0, f1);
    } else if (tid < NW + NB) {
        int t = tid - NW;
        int o = t >> 3, l = t & 7;
        const float* src = B_all + ((size_t)l * DOUT + o) * RRK;  // 16 contiguous floats
        float4 f0 = *(const float4*)(src + 0);
        float4 f1 = *(const float4*)(src + 4);
        float4 f2 = *(const float4*)(src + 8);
        float4 f3 = *(const float4*)(src + 12);
        unsigned short* dst = wcat + (size_t)o * KCAT + DIN + l * RRK;
        *(uint4*)(dst + 0) = pack8(f0, f1);
        *(uint4*)(dst + 8) = pack8(f2, f3);
    } else if (tid < NW + NB + NA) {
        int e = (tid - NW - NB) * 8;
        float4 f0 = *(const float4*)(A_all + e);
        float4 f1 = *(const float4*)(A_all + e + 4);
        *(uint4*)(acat + e) = pack8(f0, f1);
    }
}

// ---------------------------------------------------------------------------
// P1: convert x (fp32) -> xcat[:, 0:DIN] (bf16), ld = KCAT
// ---------------------------------------------------------------------------
__global__ __launch_bounds__(256) void conv_x(const float* __restrict__ x,
                                              unsigned short* __restrict__ xcat) {
    size_t e = ((size_t)blockIdx.x * 256 + threadIdx.x) * 8;  // grid sized exactly
    int n = (int)(e / DIN), k = (int)(e % DIN);
    float4 f0 = *(const float4*)(x + e);
    float4 f1 = *(const float4*)(x + e + 4);
    *(uint4*)(xcat + (size_t)n * KCAT + k) = pack8(f0, f1);
}

// ---------------------------------------------------------------------------
// P2: u_all = xcat[:, :DIN] @ Acat^T  (N x 128, K=2048, bf16 MFMA),
//     mask by lora_idx, * SCALE, write bf16 -> xcat[:, DIN:KCAT]
// ---------------------------------------------------------------------------
__global__ __launch_bounds__(256) void u_gemm(const unsigned short* __restrict__ xcat,
                                              const unsigned short* __restrict__ acat,
                                              const int* __restrict__ lidx,
                                              unsigned short* __restrict__ xcat_w) {
    __shared__ short As[128 * 32];
    __shared__ short Bs[128 * 32];
    const int tid = threadIdx.x;
    const int lane = tid & 63, wv = tid >> 6;
    const int wm = wv >> 1, wn = wv & 1;
    const int quad = lane >> 4, lm = lane & 15;
    const int row0 = blockIdx.x * 128;

    f32x4 acc[4][4];
    f32x4 zero = {0.f, 0.f, 0.f, 0.f};
#pragma unroll
    for (int i = 0; i < 4; ++i)
#pragma unroll
        for (int j = 0; j < 4; ++j) acc[i][j] = zero;

    for (int kt = 0; kt < DIN / 32; ++kt) {
        const unsigned short* ga = xcat + (size_t)row0 * KCAT + kt * 32;
        const unsigned short* gb = acat + kt * 32;
        __syncthreads();
#pragma unroll
        for (int it = 0; it < 2; ++it) {
            int cw = it * 4 + wv;
            int c = cw * 64 + lane;
            async16(ga + (size_t)(c >> 2) * KCAT + (c & 3) * 8, (void*)(As + cw * 512));
            async16(gb + (size_t)(c >> 2) * DIN + (c & 3) * 8, (void*)(Bs + cw * 512));
        }
        __syncthreads();
        bf16x8 a[4], b[4];
#pragma unroll
        for (int mi = 0; mi < 4; ++mi)
            a[mi] = *(const bf16x8*)&As[(wm * 64 + mi * 16 + lm) * 32 + quad * 8];
#pragma unroll
        for (int ni = 0; ni < 4; ++ni)
            b[ni] = *(const bf16x8*)&Bs[(wn * 64 + ni * 16 + lm) * 32 + quad * 8];
#pragma unroll
        for (int mi = 0; mi < 4; ++mi)
#pragma unroll
            for (int ni = 0; ni < 4; ++ni)
                acc[mi][ni] = __builtin_amdgcn_mfma_f32_16x16x32_bf16(a[mi], b[ni], acc[mi][ni], 0, 0, 0);
    }

#pragma unroll
    for (int mi = 0; mi < 4; ++mi) {
#pragma unroll
        for (int e = 0; e < 4; ++e) {
            int t = row0 + wm * 64 + mi * 16 + quad * 4 + e;
            int l = lidx[t];
#pragma unroll
            for (int ni = 0; ni < 4; ++ni) {
                int j = wn * 64 + ni * 16 + lm;  // j = l*16 + r index
                float v = ((j >> 4) == l) ? acc[mi][ni][e] * SCALE : 0.0f;
                xcat_w[(size_t)t * KCAT + DIN + j] = f2bf(v);
            }
        }
    }
}

// ---------------------------------------------------------------------------
// G: out = xcat @ Wcat^T + b   (N x DOUT, K = KCAT = 2176)
//    m97 structure: 128x128 tile, BK=32, global_load_lds width 16, 4 waves 2x2
// ---------------------------------------------------------------------------
__global__ __launch_bounds__(256) void gemm_main(const unsigned short* __restrict__ xcat,
                                                 const unsigned short* __restrict__ wcat,
                                                 const float* __restrict__ bias,
                                                 float* __restrict__ out) {
    __shared__ short As[128 * 32];
    __shared__ short Bs[128 * 32];
    const int tid = threadIdx.x;
    const int lane = tid & 63, wv = tid >> 6;
    const int wm = wv >> 1, wn = wv & 1;
    const int quad = lane >> 4, lm = lane & 15;
    const int col0 = blockIdx.x * 128;
    const int row0 = blockIdx.y * 128;

    f32x4 acc[4][4];
    f32x4 zero = {0.f, 0.f, 0.f, 0.f};
#pragma unroll
    for (int i = 0; i < 4; ++i)
#pragma unroll
        for (int j = 0; j < 4; ++j) acc[i][j] = zero;

    for (int kt = 0; kt < KCAT / 32; ++kt) {
        const unsigned short* ga = xcat + (size_t)row0 * KCAT + kt * 32;
        const unsigned short* gb = wcat + (size_t)col0 * KCAT + kt * 32;
        __syncthreads();
#pragma unroll
        for (int it = 0; it < 2; ++it) {
            int cw = it * 4 + wv;
            int c = cw * 64 + lane;
            async16(ga + (size_t)(c >> 2) * KCAT + (c & 3) * 8, (void*)(As + cw * 512));
            async16(gb + (size_t)(c >> 2) * KCAT + (c & 3) * 8, (void*)(Bs + cw * 512));
        }
        __syncthreads();
        bf16x8 a[4], b[4];
#pragma unroll
        for (int mi = 0; mi < 4; ++mi)
            a[mi] = *(const bf16x8*)&As[(wm * 64 + mi * 16 + lm) * 32 + quad * 8];
#pragma unroll
        for (int ni = 0; ni < 4; ++ni)
            b[ni] = *(const bf16x8*)&Bs[(wn * 64 + ni * 16 + lm) * 32 + quad * 8];
#pragma unroll
        for (int mi = 0; mi < 4; ++mi)
#pragma unroll
            for (int ni = 0; ni < 4; ++ni)
                acc[mi][ni] = __builtin_amdgcn_mfma_f32_16x16x32_bf16(a[mi], b[ni], acc[mi][ni], 0, 0, 0);
    }

#pragma unroll
    for (int ni = 0; ni < 4; ++ni) {
        int col = col0 + wn * 64 + ni * 16 + lm;
        float bv = bias[col];
#pragma unroll
        for (int mi = 0; mi < 4; ++mi) {
            int rbase = row0 + wm * 64 + mi * 16 + quad * 4;
#pragma unroll
            for (int e = 0; e < 4; ++e)
                out[(size_t)(rbase + e) * DOUT + col] = acc[mi][ni][e] + bv;
        }
    }
}

extern "C" void kernel_launch(void* const* d_in, const int* in_sizes, int n_in,
                              void* d_out, int out_size, void* d_ws, size_t ws_size,
                              hipStream_t stream) {
    const float* x     = (const float*)d_in[0];
    const float* W     = (const float*)d_in[1];
    const float* bias  = (const float*)d_in[2];
    const float* A_all = (const float*)d_in[3];
    const float* B_all = (const float*)d_in[4];
    const int*   lidx  = (const int*)d_in[5];
    float* out = (float*)d_out;

    char* ws = (char*)d_ws;
    unsigned short* xcat = (unsigned short*)ws;                                   // N_TOK*KCAT bf16
    unsigned short* wcat = (unsigned short*)(ws + (size_t)N_TOK * KCAT * 2);      // DOUT*KCAT bf16
    unsigned short* acat = (unsigned short*)(ws + (size_t)N_TOK * KCAT * 2
                                                + (size_t)DOUT * KCAT * 2);       // 128*DIN bf16

    prep_w<<<2240, 256, 0, stream>>>(W, A_all, B_all, wcat, acat);
    conv_x<<<(N_TOK * (DIN / 8)) / 256, 256, 0, stream>>>(x, xcat);
    u_gemm<<<N_TOK / 128, 256, 0, stream>>>(xcat, acat, lidx, xcat);
    gemm_main<<<dim3(DOUT / 128, N_TOK / 128), 256, 0, stream>>>(xcat, wcat, bias, out);
}

// Round 2
// 853.711 us; speedup vs baseline: 1.0108x; 1.0108x over previous
//
#include <hip/hip_runtime.h>
#include <stdint.h>

#define N_TOK 32768
#define DIN   2048
#define DOUT  2048
#define LAD   8
#define RRK   16
#define KCAT  2176   /* DIN + LAD*RRK */
#define SCALE 2.0f

typedef __attribute__((ext_vector_type(8))) short bf16x8;
typedef __attribute__((ext_vector_type(4))) float f32x4;

__device__ __forceinline__ unsigned short f2bf(float f) {
    union { float f; unsigned u; } c; c.f = f;
    return (unsigned short)((c.u + 0x7FFFu + ((c.u >> 16) & 1u)) >> 16);
}

__device__ __forceinline__ uint4 pack8(float4 a, float4 b) {
    union { unsigned short s[8]; uint4 v; } u;
    u.s[0] = f2bf(a.x); u.s[1] = f2bf(a.y); u.s[2] = f2bf(a.z); u.s[3] = f2bf(a.w);
    u.s[4] = f2bf(b.x); u.s[5] = f2bf(b.y); u.s[6] = f2bf(b.z); u.s[7] = f2bf(b.w);
    return u.v;
}

__device__ __forceinline__ void async16(const void* g, void* l) {
    __builtin_amdgcn_global_load_lds(
        (const __attribute__((address_space(1))) void*)g,
        (__attribute__((address_space(3))) void*)l, 16, 0, 0);
}

// LDS tile layout: row-major [128][32] shorts, 64 B/row = 4 x 16B granules.
// XOR swizzle: data granule g of row r lives at LDS granule g ^ ((r>>1)&3).
// -> any 8 consecutive lanes of a b128 fragment read hit 8 distinct 4-bank
//    groups (2 lanes/bank = free per m136) instead of 2 groups (4-way).

// ---------------------------------------------------------------------------
// P0: build Wcat = [bf16(W) | B_all gathered as [o][l*16+r]]  (DOUT x KCAT)
//     and Acat = bf16(A_all) viewed flat as [128][DIN]
// ---------------------------------------------------------------------------
__global__ __launch_bounds__(256) void prep_w(const float* __restrict__ W,
                                              const float* __restrict__ A_all,
                                              const float* __restrict__ B_all,
                                              unsigned short* __restrict__ wcat,
                                              unsigned short* __restrict__ acat) {
    const int NW = DOUT * DIN / 8;
    const int NB = DOUT * LAD;
    const int NA = LAD * RRK * DIN / 8;
    int tid = blockIdx.x * 256 + threadIdx.x;
    if (tid < NW) {
        int e = tid * 8;
        int o = e / DIN, k = e % DIN;
        float4 f0 = *(const float4*)(W + e);
        float4 f1 = *(const float4*)(W + e + 4);
        *(uint4*)(wcat + (size_t)o * KCAT + k) = pack8(f0, f1);
    } else if (tid < NW + NB) {
        int t = tid - NW;
        int o = t >> 3, l = t & 7;
        const float* src = B_all + ((size_t)l * DOUT + o) * RRK;
        float4 f0 = *(const float4*)(src + 0);
        float4 f1 = *(const float4*)(src + 4);
        float4 f2 = *(const float4*)(src + 8);
        float4 f3 = *(const float4*)(src + 12);
        unsigned short* dst = wcat + (size_t)o * KCAT + DIN + l * RRK;
        *(uint4*)(dst + 0) = pack8(f0, f1);
        *(uint4*)(dst + 8) = pack8(f2, f3);
    } else if (tid < NW + NB + NA) {
        int e = (tid - NW - NB) * 8;
        float4 f0 = *(const float4*)(A_all + e);
        float4 f1 = *(const float4*)(A_all + e + 4);
        *(uint4*)(acat + e) = pack8(f0, f1);
    }
}

// ---------------------------------------------------------------------------
// P1: convert x (fp32) -> xcat[:, 0:DIN] (bf16), ld = KCAT
// ---------------------------------------------------------------------------
__global__ __launch_bounds__(256) void conv_x(const float* __restrict__ x,
                                              unsigned short* __restrict__ xcat) {
    size_t e = ((size_t)blockIdx.x * 256 + threadIdx.x) * 8;
    int n = (int)(e / DIN), k = (int)(e % DIN);
    float4 f0 = *(const float4*)(x + e);
    float4 f1 = *(const float4*)(x + e + 4);
    *(uint4*)(xcat + (size_t)n * KCAT + k) = pack8(f0, f1);
}

// ---------------------------------------------------------------------------
// P2: u_all = xcat[:, :DIN] @ Acat^T  (N x 128, K=2048, bf16 MFMA),
//     mask by lora_idx, * SCALE, write bf16 -> xcat[:, DIN:KCAT]
// ---------------------------------------------------------------------------
__global__ __launch_bounds__(256) void u_gemm(const unsigned short* __restrict__ xcat,
                                              const unsigned short* __restrict__ acat,
                                              const int* __restrict__ lidx,
                                              unsigned short* __restrict__ xcat_w) {
    __shared__ short As[128 * 32];
    __shared__ short Bs[128 * 32];
    const int tid = threadIdx.x;
    const int lane = tid & 63, wv = tid >> 6;
    const int wm = wv >> 1, wn = wv & 1;
    const int quad = lane >> 4, lm = lane & 15;
    const int row0 = blockIdx.x * 128;
    // staging: lane's source granule (XOR-swizzle, per-lane constant)
    const int sg = (lane & 3) ^ ((lane >> 3) & 3);
    // fragment read: swizzled LDS granule
    const int swg = quad ^ ((lm >> 1) & 3);

    f32x4 acc[4][4];
    f32x4 zero = {0.f, 0.f, 0.f, 0.f};
#pragma unroll
    for (int i = 0; i < 4; ++i)
#pragma unroll
        for (int j = 0; j < 4; ++j) acc[i][j] = zero;

    for (int kt = 0; kt < DIN / 32; ++kt) {
        const unsigned short* ga = xcat + (size_t)row0 * KCAT + kt * 32;
        const unsigned short* gb = acat + kt * 32;
        __syncthreads();
#pragma unroll
        for (int it = 0; it < 2; ++it) {
            int cw = it * 4 + wv;
            int r = (cw * 64 + lane) >> 2;
            async16(ga + (size_t)r * KCAT + sg * 8, (void*)(As + cw * 512));
            async16(gb + (size_t)r * DIN + sg * 8, (void*)(Bs + cw * 512));
        }
        __syncthreads();
        bf16x8 a[4], b[4];
#pragma unroll
        for (int mi = 0; mi < 4; ++mi)
            a[mi] = *(const bf16x8*)&As[(wm * 64 + mi * 16 + lm) * 32 + swg * 8];
#pragma unroll
        for (int ni = 0; ni < 4; ++ni)
            b[ni] = *(const bf16x8*)&Bs[(wn * 64 + ni * 16 + lm) * 32 + swg * 8];
#pragma unroll
        for (int mi = 0; mi < 4; ++mi)
#pragma unroll
            for (int ni = 0; ni < 4; ++ni)
                acc[mi][ni] = __builtin_amdgcn_mfma_f32_16x16x32_bf16(a[mi], b[ni], acc[mi][ni], 0, 0, 0);
    }

#pragma unroll
    for (int mi = 0; mi < 4; ++mi) {
#pragma unroll
        for (int e = 0; e < 4; ++e) {
            int t = row0 + wm * 64 + mi * 16 + quad * 4 + e;
            int l = lidx[t];
#pragma unroll
            for (int ni = 0; ni < 4; ++ni) {
                int j = wn * 64 + ni * 16 + lm;
                float v = ((j >> 4) == l) ? acc[mi][ni][e] * SCALE : 0.0f;
                xcat_w[(size_t)t * KCAT + DIN + j] = f2bf(v);
            }
        }
    }
}

// ---------------------------------------------------------------------------
// G: out = xcat @ Wcat^T + b   (N x DOUT, K = KCAT = 2176)
// ---------------------------------------------------------------------------
__global__ __launch_bounds__(256) void gemm_main(const unsigned short* __restrict__ xcat,
                                                 const unsigned short* __restrict__ wcat,
                                                 const float* __restrict__ bias,
                                                 float* __restrict__ out) {
    __shared__ short As[128 * 32];
    __shared__ short Bs[128 * 32];
    const int tid = threadIdx.x;
    const int lane = tid & 63, wv = tid >> 6;
    const int wm = wv >> 1, wn = wv & 1;
    const int quad = lane >> 4, lm = lane & 15;
    const int col0 = blockIdx.x * 128;
    const int row0 = blockIdx.y * 128;
    const int sg = (lane & 3) ^ ((lane >> 3) & 3);
    const int swg = quad ^ ((lm >> 1) & 3);

    f32x4 acc[4][4];
    f32x4 zero = {0.f, 0.f, 0.f, 0.f};
#pragma unroll
    for (int i = 0; i < 4; ++i)
#pragma unroll
        for (int j = 0; j < 4; ++j) acc[i][j] = zero;

    for (int kt = 0; kt < KCAT / 32; ++kt) {
        const unsigned short* ga = xcat + (size_t)row0 * KCAT + kt * 32;
        const unsigned short* gb = wcat + (size_t)col0 * KCAT + kt * 32;
        __syncthreads();
#pragma unroll
        for (int it = 0; it < 2; ++it) {
            int cw = it * 4 + wv;
            int r = (cw * 64 + lane) >> 2;
            async16(ga + (size_t)r * KCAT + sg * 8, (void*)(As + cw * 512));
            async16(gb + (size_t)r * KCAT + sg * 8, (void*)(Bs + cw * 512));
        }
        __syncthreads();
        bf16x8 a[4], b[4];
#pragma unroll
        for (int mi = 0; mi < 4; ++mi)
            a[mi] = *(const bf16x8*)&As[(wm * 64 + mi * 16 + lm) * 32 + swg * 8];
#pragma unroll
        for (int ni = 0; ni < 4; ++ni)
            b[ni] = *(const bf16x8*)&Bs[(wn * 64 + ni * 16 + lm) * 32 + swg * 8];
#pragma unroll
        for (int mi = 0; mi < 4; ++mi)
#pragma unroll
            for (int ni = 0; ni < 4; ++ni)
                acc[mi][ni] = __builtin_amdgcn_mfma_f32_16x16x32_bf16(a[mi], b[ni], acc[mi][ni], 0, 0, 0);
    }

#pragma unroll
    for (int ni = 0; ni < 4; ++ni) {
        int col = col0 + wn * 64 + ni * 16 + lm;
        float bv = bias[col];
#pragma unroll
        for (int mi = 0; mi < 4; ++mi) {
            int rbase = row0 + wm * 64 + mi * 16 + quad * 4;
#pragma unroll
            for (int e = 0; e < 4; ++e)
                out[(size_t)(rbase + e) * DOUT + col] = acc[mi][ni][e] + bv;
        }
    }
}

extern "C" void kernel_launch(void* const* d_in, const int* in_sizes, int n_in,
                              void* d_out, int out_size, void* d_ws, size_t ws_size,
                              hipStream_t stream) {
    const float* x     = (const float*)d_in[0];
    const float* W     = (const float*)d_in[1];
    const float* bias  = (const float*)d_in[2];
    const float* A_all = (const float*)d_in[3];
    const float* B_all = (const float*)d_in[4];
    const int*   lidx  = (const int*)d_in[5];
    float* out = (float*)d_out;

    char* ws = (char*)d_ws;
    unsigned short* xcat = (unsigned short*)ws;
    unsigned short* wcat = (unsigned short*)(ws + (size_t)N_TOK * KCAT * 2);
    unsigned short* acat = (unsigned short*)(ws + (size_t)N_TOK * KCAT * 2
                                                + (size_t)DOUT * KCAT * 2);

    prep_w<<<2240, 256, 0, stream>>>(W, A_all, B_all, wcat, acat);
    conv_x<<<(N_TOK * (DIN / 8)) / 256, 256, 0, stream>>>(x, xcat);
    u_gemm<<<N_TOK / 128, 256, 0, stream>>>(xcat, acat, lidx, xcat);
    gemm_main<<<dim3(DOUT / 128, N_TOK / 128), 256, 0, stream>>>(xcat, wcat, bias, out);
}